// Round 1
// baseline (337.261 us; speedup 1.0000x reference)
//
#include <hip/hip_runtime.h>

// Problem constants
#define B_ 4
#define L_ 2048
#define D_ 1024
#define M_FLAT (B_*L_)   // 8192

#define TILE 128
#define BKK 32

typedef unsigned short bf16_t;
typedef __attribute__((ext_vector_type(8))) short bf16x8;
typedef __attribute__((ext_vector_type(4))) float f32x4;

// ---- bf16 helpers (bit-level, RNE) ----
__device__ __forceinline__ bf16_t f2bf(float f) {
  union { float f; unsigned int u; } c; c.f = f;
  unsigned int u = c.u;
  unsigned int r = (u + 0x7fffu + ((u >> 16) & 1u)) >> 16;
  return (bf16_t)r;
}
__device__ __forceinline__ float bf2f(bf16_t h) {
  union { unsigned int u; float f; } c; c.u = ((unsigned int)h) << 16;
  return c.f;
}

// ---- async global->LDS (16B per lane, wave-uniform LDS base) ----
__device__ __forceinline__ void gload_lds16(const bf16_t* g, bf16_t* l) {
  __builtin_amdgcn_global_load_lds(
      (const __attribute__((address_space(1))) unsigned int*)g,
      (__attribute__((address_space(3))) unsigned int*)l, 16, 0, 0);
}

// ---- elementwise fp32 -> bf16 convert, 8 elts/thread ----
__global__ __launch_bounds__(256) void cvt_bf16(const float* __restrict__ in,
                                                bf16_t* __restrict__ out) {
  size_t i = (size_t)blockIdx.x * 256 + threadIdx.x;
  const float4* p = (const float4*)in + i * 2;
  float4 a = p[0], b = p[1];
  union { bf16_t h[8]; uint4 u; } r;
  r.h[0] = f2bf(a.x); r.h[1] = f2bf(a.y); r.h[2] = f2bf(a.z); r.h[3] = f2bf(a.w);
  r.h[4] = f2bf(b.x); r.h[5] = f2bf(b.y); r.h[6] = f2bf(b.z); r.h[7] = f2bf(b.w);
  ((uint4*)out)[i] = r.u;
}

// ---- 1024x1024 fp32 -> transposed bf16 (W -> W^T) ----
__global__ __launch_bounds__(256) void transpose_cvt(const float* __restrict__ Wsrc,
                                                     bf16_t* __restrict__ Wt) {
  __shared__ float t[32][33];
  int c0 = blockIdx.x * 32, r0 = blockIdx.y * 32;
  int tx = threadIdx.x, ty = threadIdx.y;   // block (32,8)
#pragma unroll
  for (int i = 0; i < 4; i++)
    t[ty + i * 8][tx] = Wsrc[(size_t)(r0 + ty + i * 8) * D_ + c0 + tx];
  __syncthreads();
#pragma unroll
  for (int i = 0; i < 4; i++)
    Wt[(size_t)(c0 + ty + i * 8) * D_ + r0 + tx] = f2bf(t[tx][ty + i * 8]);
}

// ---- reduce per-tile row maxes (32 per row) to one max per row ----
__global__ __launch_bounds__(256) void rowmax_k(const float* __restrict__ tm,
                                                float* __restrict__ rm) {
  int r = blockIdx.x * 256 + threadIdx.x;  // 8192 rows total
  float m = -3.0e38f;
#pragma unroll
  for (int t = 0; t < 32; t++) m = fmaxf(m, tm[(size_t)r * 32 + t]);
  rm[r] = m;
}

// ---- per-row softmax: P = exp(S - m) in place (bf16), write row sum ----
__global__ __launch_bounds__(256) void softmax_row(bf16_t* __restrict__ S,
                                                   const float* __restrict__ rm,
                                                   float* __restrict__ rs) {
  int row = blockIdx.x;           // 8192 rows
  int tid = threadIdx.x;          // 256 threads * 8 elts = 2048
  float m = rm[row];
  uint4* p = (uint4*)(S + (size_t)row * L_);
  union { uint4 u; bf16_t h[8]; } v;
  v.u = p[tid];
  float sum = 0.f;
#pragma unroll
  for (int j = 0; j < 8; j++) {
    float e = __expf(bf2f(v.h[j]) - m);
    bf16_t eb = f2bf(e);
    v.h[j] = eb;
    sum += bf2f(eb);   // sum the rounded values for consistency with stored P
  }
  p[tid] = v.u;
#pragma unroll
  for (int off = 32; off; off >>= 1) sum += __shfl_down(sum, off, 64);
  __shared__ float wsum[4];
  if ((tid & 63) == 0) wsum[tid >> 6] = sum;
  __syncthreads();
  if (tid == 0) rs[row] = wsum[0] + wsum[1] + wsum[2] + wsum[3];
}

// ---- generic 128x128 bf16 GEMM: C = A(MxK) * Bt(NxK)^T, templated epilogue ----
#define M_BF16 0  // out bf16 = (acc + bias[c]) * scale
#define M_VT   1  // out bf16 transposed per batch: Vt[b][c][r%L] = acc + bias[c]
#define M_S    2  // out bf16 = mask? acc : -1e20 ; per-tile rowmax
#define M_PV   3  // out bf16 = acc / rsum[r]
#define M_OUT  4  // out fp32 = acc + bias[c]

template <int MODE>
__global__ __launch_bounds__(256)
void gemm_bt(const bf16_t* __restrict__ Ag, int lda, long strA,
             const bf16_t* __restrict__ Bg, int ldb, long strB,
             void* __restrict__ outp, long strO, int ldo,
             const float* __restrict__ bias, float scale,
             const float* __restrict__ rsum,
             const int* __restrict__ maskp,
             float* __restrict__ tmax,
             int K) {
  __shared__ __align__(16) bf16_t sAt[TILE * BKK];
  __shared__ __align__(16) bf16_t sBt[TILE * BKK];
  const int tid = threadIdx.x;
  const int lane = tid & 63;
  const int w = tid >> 6;
  const int z = blockIdx.z;
  const bf16_t* A = Ag + (size_t)z * strA;
  const bf16_t* Bt = Bg + (size_t)z * strB;
  const int mbase = blockIdx.y * TILE;
  const int nbase = blockIdx.x * TILE;

  // staging: chunk c = issue*256 + w*64 + lane ; row = c>>2, slot = c&3 (8 bf16 = 16B)
  const int srow = w * 16 + (lane >> 2);
  const int sslot = (lane & 3) * 8;
  const bf16_t* ga0 = A + (size_t)(mbase + srow) * lda + sslot;
  const bf16_t* ga1 = ga0 + (size_t)64 * lda;
  const bf16_t* gb0 = Bt + (size_t)(nbase + srow) * ldb + sslot;
  const bf16_t* gb1 = gb0 + (size_t)64 * ldb;
  bf16_t* la0 = &sAt[w * 512];
  bf16_t* la1 = &sAt[2048 + w * 512];
  bf16_t* lb0 = &sBt[w * 512];
  bf16_t* lb1 = &sBt[2048 + w * 512];

  f32x4 acc[4][4] = {};

  const int wrow = (w >> 1) * 64, wcol = (w & 1) * 64;
  const int fr = lane & 15, fs = lane >> 4;

  const int nk = K / BKK;
  for (int kt = 0; kt < nk; ++kt) {
    gload_lds16(ga0, la0);
    gload_lds16(ga1, la1);
    gload_lds16(gb0, lb0);
    gload_lds16(gb1, lb1);
    ga0 += BKK; ga1 += BKK; gb0 += BKK; gb1 += BKK;
    __syncthreads();   // drains vmcnt -> LDS tile ready
    bf16x8 af[4], bfv[4];
#pragma unroll
    for (int m = 0; m < 4; m++)
      af[m] = *(const bf16x8*)&sAt[(wrow + m * 16 + fr) * BKK + fs * 8];
#pragma unroll
    for (int n = 0; n < 4; n++)
      bfv[n] = *(const bf16x8*)&sBt[(wcol + n * 16 + fr) * BKK + fs * 8];
#pragma unroll
    for (int m = 0; m < 4; m++)
#pragma unroll
      for (int n = 0; n < 4; n++)
        acc[m][n] = __builtin_amdgcn_mfma_f32_16x16x32_bf16(af[m], bfv[n], acc[m][n], 0, 0, 0);
    __syncthreads();   // protect LDS from next-iteration staging
  }

  // ---- epilogues ----  C/D frag: col = lane&15 (fr), row = fs*4 + j
  if constexpr (MODE == M_BF16) {
    bf16_t* o = (bf16_t*)outp + (size_t)z * strO;
#pragma unroll
    for (int n = 0; n < 4; n++) {
      int c = nbase + wcol + n * 16 + fr;
      float bv = bias[c];
#pragma unroll
      for (int m = 0; m < 4; m++) {
        int r0 = mbase + wrow + m * 16 + fs * 4;
#pragma unroll
        for (int j = 0; j < 4; j++)
          o[(size_t)(r0 + j) * ldo + c] = f2bf((acc[m][n][j] + bv) * scale);
      }
    }
  } else if constexpr (MODE == M_VT) {
    bf16_t* o = (bf16_t*)outp;
#pragma unroll
    for (int n = 0; n < 4; n++) {
      int c = nbase + wcol + n * 16 + fr;
      float bv = bias[c];
#pragma unroll
      for (int m = 0; m < 4; m++) {
        int rg = mbase + wrow + m * 16 + fs * 4;
        int b = rg >> 11;            // / L_
        int rl = rg & (L_ - 1);
        union { bf16_t h[4]; ushort4 u; } pk;
#pragma unroll
        for (int j = 0; j < 4; j++) pk.h[j] = f2bf(acc[m][n][j] + bv);
        *(ushort4*)&o[(size_t)b * D_ * L_ + (size_t)c * L_ + rl] = pk.u;
      }
    }
  } else if constexpr (MODE == M_S) {
    bf16_t* o = (bf16_t*)outp + (size_t)z * strO;
    const int* mk = maskp + (size_t)z * L_ * L_;
    float* tm = tmax + (size_t)z * L_ * 32;
#pragma unroll
    for (int m = 0; m < 4; m++) {
#pragma unroll
      for (int j = 0; j < 4; j++) {
        int r = mbase + wrow + m * 16 + fs * 4 + j;
        float rowm = -3.0e38f;
#pragma unroll
        for (int n = 0; n < 4; n++) {
          int c = nbase + wcol + n * 16 + fr;
          float v = acc[m][n][j];
          if (mk[(size_t)r * L_ + c] == 0) v = -1e20f;
          rowm = fmaxf(rowm, v);
          o[(size_t)r * ldo + c] = f2bf(v);
        }
#pragma unroll
        for (int off = 8; off; off >>= 1) rowm = fmaxf(rowm, __shfl_xor(rowm, off, 16));
        if (fr == 0) tm[r * 32 + blockIdx.x * 2 + (w & 1)] = rowm;
      }
    }
  } else if constexpr (MODE == M_PV) {
    bf16_t* o = (bf16_t*)outp + (size_t)z * strO;
    const float* rs = rsum + (size_t)z * L_;
#pragma unroll
    for (int m = 0; m < 4; m++) {
#pragma unroll
      for (int j = 0; j < 4; j++) {
        int r = mbase + wrow + m * 16 + fs * 4 + j;
        float inv = 1.0f / rs[r];
#pragma unroll
        for (int n = 0; n < 4; n++) {
          int c = nbase + wcol + n * 16 + fr;
          o[(size_t)r * ldo + c] = f2bf(acc[m][n][j] * inv);
        }
      }
    }
  } else {  // M_OUT
    float* o = (float*)outp;
#pragma unroll
    for (int n = 0; n < 4; n++) {
      int c = nbase + wcol + n * 16 + fr;
      float bv = bias[c];
#pragma unroll
      for (int m = 0; m < 4; m++) {
        int r0 = mbase + wrow + m * 16 + fs * 4;
#pragma unroll
        for (int j = 0; j < 4; j++)
          o[(size_t)(r0 + j) * ldo + c] = acc[m][n][j] + bv;
      }
    }
  }
}

extern "C" void kernel_launch(void* const* d_in, const int* in_sizes, int n_in,
                              void* d_out, int out_size, void* d_ws, size_t ws_size,
                              hipStream_t stream) {
  const float* query = (const float*)d_in[0];
  const float* keyi  = (const float*)d_in[1];
  const float* value = (const float*)d_in[2];
  const int*   mask  = (const int*)d_in[3];
  const float* Wq = (const float*)d_in[4];
  const float* bq = (const float*)d_in[5];
  const float* Wk = (const float*)d_in[6];
  const float* bk = (const float*)d_in[7];
  const float* Wv = (const float*)d_in[8];
  const float* bv = (const float*)d_in[9];
  const float* Wo = (const float*)d_in[10];
  const float* bo = (const float*)d_in[11];

  bf16_t* ws = (bf16_t*)d_ws;
  const size_t NE = (size_t)M_FLAT * D_;  // 8388608 elts
  const size_t WE = (size_t)D_ * D_;      // 1048576 elts
  bf16_t* XQ  = ws;                 // bf16 query  (dead after Q proj)
  bf16_t* XK  = ws + NE;            // bf16 key    (dead after K proj)
  bf16_t* XV  = ws + 2 * NE;        // bf16 value  (dead after V proj)
  bf16_t* WQT = ws + 3 * NE;
  bf16_t* WKT = WQT + WE;
  bf16_t* WVT = WKT + WE;
  bf16_t* WOT = WVT + WE;
  bf16_t* Qb  = WOT + WE;           // (B*L, D) bf16, pre-scaled 1/32
  bf16_t* Kb  = Qb + NE;            // (B*L, D) bf16
  bf16_t* Vt  = Kb + NE;            // per batch (D, L) bf16
  bf16_t* Sb  = ws;                 // S/P (B, L, L) bf16  — overlaps XQ+XK
  bf16_t* Ob  = ws + 2 * NE;        // attn out (B*L, D)   — overlaps XV
  float* tmaxp = (float*)(Vt + NE);               // (B*L, 32)
  float* rowm  = tmaxp + (size_t)B_ * L_ * 32;    // (B*L)
  float* rsump = rowm + (size_t)B_ * L_;          // (B*L)

  // 1) converts
  cvt_bf16<<<dim3(4096), dim3(256), 0, stream>>>(query, XQ);
  cvt_bf16<<<dim3(4096), dim3(256), 0, stream>>>(keyi, XK);
  cvt_bf16<<<dim3(4096), dim3(256), 0, stream>>>(value, XV);
  // 2) weight transposes
  transpose_cvt<<<dim3(32, 32), dim3(32, 8), 0, stream>>>(Wq, WQT);
  transpose_cvt<<<dim3(32, 32), dim3(32, 8), 0, stream>>>(Wk, WKT);
  transpose_cvt<<<dim3(32, 32), dim3(32, 8), 0, stream>>>(Wv, WVT);
  transpose_cvt<<<dim3(32, 32), dim3(32, 8), 0, stream>>>(Wo, WOT);
  // 3) projections
  dim3 pg(D_ / TILE, M_FLAT / TILE, 1);  // (8,64,1)
  gemm_bt<M_BF16><<<pg, 256, 0, stream>>>(XQ, D_, 0, WQT, D_, 0, Qb, 0, D_,
                                          bq, 0.03125f, nullptr, nullptr, nullptr, D_);
  gemm_bt<M_BF16><<<pg, 256, 0, stream>>>(XK, D_, 0, WKT, D_, 0, Kb, 0, D_,
                                          bk, 1.0f, nullptr, nullptr, nullptr, D_);
  gemm_bt<M_VT><<<pg, 256, 0, stream>>>(XV, D_, 0, WVT, D_, 0, Vt, 0, L_,
                                        bv, 1.0f, nullptr, nullptr, nullptr, D_);
  // 4) S = Q K^T (scale folded into Q) + mask + per-tile rowmax
  dim3 sg(L_ / TILE, L_ / TILE, B_);  // (16,16,4)
  gemm_bt<M_S><<<sg, 256, 0, stream>>>(Qb, D_, (long)L_ * D_, Kb, D_, (long)L_ * D_,
                                       Sb, (long)L_ * L_, L_,
                                       nullptr, 1.0f, nullptr, mask, tmaxp, D_);
  // 5) row max reduce
  rowmax_k<<<dim3(32), dim3(256), 0, stream>>>(tmaxp, rowm);
  // 6) softmax rows (P in place, row sums)
  softmax_row<<<dim3(B_ * L_), dim3(256), 0, stream>>>(Sb, rowm, rsump);
  // 7) O = P V  (divide by row sum in epilogue)
  dim3 vg(D_ / TILE, L_ / TILE, B_);  // (8,16,4)
  gemm_bt<M_PV><<<vg, 256, 0, stream>>>(Sb, L_, (long)L_ * L_, Vt, L_, (long)D_ * L_,
                                        Ob, (long)L_ * D_, D_,
                                        nullptr, 1.0f, rsump, nullptr, nullptr, L_);
  // 8) final projection -> fp32 d_out
  gemm_bt<M_OUT><<<pg, 256, 0, stream>>>(Ob, D_, 0, WOT, D_, 0, d_out, 0, D_,
                                         bo, 1.0f, nullptr, nullptr, nullptr, D_);
}

// Round 2
// 279.423 us; speedup vs baseline: 1.2070x; 1.2070x over previous
//
#include <hip/hip_runtime.h>

// Problem constants
#define B_ 4
#define L_ 2048
#define D_ 1024
#define M_FLAT (B_*L_)   // 8192

typedef unsigned short bf16_t;
typedef __attribute__((ext_vector_type(8))) short bf16x8;
typedef __attribute__((ext_vector_type(4))) float f32x4;

// ---- bf16 helpers (bit-level, RNE) ----
__device__ __forceinline__ bf16_t f2bf(float f) {
  union { float f; unsigned int u; } c; c.f = f;
  unsigned int u = c.u;
  unsigned int r = (u + 0x7fffu + ((u >> 16) & 1u)) >> 16;
  return (bf16_t)r;
}
__device__ __forceinline__ float bf2f(bf16_t h) {
  union { unsigned int u; float f; } c; c.u = ((unsigned int)h) << 16;
  return c.f;
}

// ---- async global->LDS (16B per lane, wave-uniform LDS base) ----
__device__ __forceinline__ void gload_lds16(const bf16_t* g, bf16_t* l) {
  __builtin_amdgcn_global_load_lds(
      (const __attribute__((address_space(1))) unsigned int*)g,
      (__attribute__((address_space(3))) unsigned int*)l, 16, 0, 0);
}

#define BARRIER() do { asm volatile("" ::: "memory"); \
                       __builtin_amdgcn_s_barrier();  \
                       asm volatile("" ::: "memory"); } while (0)
#define VMW4() asm volatile("s_waitcnt vmcnt(4)" ::: "memory")

// ---- elementwise fp32 -> bf16 convert, 8 elts/thread ----
__global__ __launch_bounds__(256) void cvt_bf16(const float* __restrict__ in,
                                                bf16_t* __restrict__ out) {
  size_t i = (size_t)blockIdx.x * 256 + threadIdx.x;
  const float4* p = (const float4*)in + i * 2;
  float4 a = p[0], b = p[1];
  union { bf16_t h[8]; uint4 u; } r;
  r.h[0] = f2bf(a.x); r.h[1] = f2bf(a.y); r.h[2] = f2bf(a.z); r.h[3] = f2bf(a.w);
  r.h[4] = f2bf(b.x); r.h[5] = f2bf(b.y); r.h[6] = f2bf(b.z); r.h[7] = f2bf(b.w);
  ((uint4*)out)[i] = r.u;
}

// ---- 1024x1024 fp32 -> transposed bf16 (W -> W^T) ----
__global__ __launch_bounds__(256) void transpose_cvt(const float* __restrict__ Wsrc,
                                                     bf16_t* __restrict__ Wt) {
  __shared__ float t[32][33];
  int c0 = blockIdx.x * 32, r0 = blockIdx.y * 32;
  int tx = threadIdx.x, ty = threadIdx.y;   // block (32,8)
#pragma unroll
  for (int i = 0; i < 4; i++)
    t[ty + i * 8][tx] = Wsrc[(size_t)(r0 + ty + i * 8) * D_ + c0 + tx];
  __syncthreads();
#pragma unroll
  for (int i = 0; i < 4; i++)
    Wt[(size_t)(c0 + ty + i * 8) * D_ + r0 + tx] = f2bf(t[tx][ty + i * 8]);
}

// ---- reduce per-tile row maxes (32 per row) to one max per row ----
__global__ __launch_bounds__(256) void rowmax_k(const float* __restrict__ tm,
                                                float* __restrict__ rm) {
  int r = blockIdx.x * 256 + threadIdx.x;  // 8192 rows total
  float m = -3.0e38f;
#pragma unroll
  for (int t = 0; t < 32; t++) m = fmaxf(m, tm[(size_t)r * 32 + t]);
  rm[r] = m;
}

// ---- per-row softmax: P = exp(S - m) in place (bf16), write row sum ----
__global__ __launch_bounds__(256) void softmax_row(bf16_t* __restrict__ S,
                                                   const float* __restrict__ rm,
                                                   float* __restrict__ rs) {
  int row = blockIdx.x;           // 8192 rows
  int tid = threadIdx.x;          // 256 threads * 8 elts = 2048
  float m = rm[row];
  uint4* p = (uint4*)(S + (size_t)row * L_);
  union { uint4 u; bf16_t h[8]; } v;
  v.u = p[tid];
  float sum = 0.f;
#pragma unroll
  for (int j = 0; j < 8; j++) {
    float e = __expf(bf2f(v.h[j]) - m);
    bf16_t eb = f2bf(e);
    v.h[j] = eb;
    sum += bf2f(eb);
  }
  p[tid] = v.u;
#pragma unroll
  for (int off = 32; off; off >>= 1) sum += __shfl_down(sum, off, 64);
  __shared__ float wsum[4];
  if ((tid & 63) == 0) wsum[tid >> 6] = sum;
  __syncthreads();
  if (tid == 0) rs[row] = wsum[0] + wsum[1] + wsum[2] + wsum[3];
}

// ================= 256x256 8-phase BK=64 GEMM (T2+T3+T4+T5) =================
// C = A(MxK) * Bt(NxK)^T. 8 waves (2M x 4N), per-wave output 128x64.
// LDS: 2 bufs x (A 32KB + B 32KB) = 128KB. Half-tile = 128 rows x 64 K = 16KB.
// Swizzle: element (r, k) of a half lives at byte r*128 + ((k>>3)^(r&7))*16 + (k&7)*2.
// Staging schedule (race-free with 2 bufs, derived from read-completion times):
//   prologue: kt0.{A0,A1,B0,B1}, kt1.B0, kt1.A0 ; vmcnt(4); barrier
//   kt phases (quadrants (mh,nh) = (0,0),(0,1),(1,1),(1,0)):
//     ph0: stage kt+1.B1 -> buf^1 ; ph1: stage kt+1.A1 -> buf^1
//     ph2: stage kt+2.B0 -> buf   ; ph3: stage kt+2.A0 -> buf ; vmcnt(4)
//   Boundary vmcnt(4) leaves exactly {kt+2.B0, kt+2.A0} in flight -> kt+1 landed.
#define MODE_PROJ 0  // z=0: Q=(acc+bq)/32; z=1: K=acc+bk; z=2: V transposed
#define MODE_S    1  // mask ? acc : -1e20 ; per-tile rowmax partials
#define MODE_PV   2  // acc / rsum[r]
#define MODE_OUT  3  // fp32 acc + bias

template <int MODE>
__global__ __launch_bounds__(512, 1)
void gemm256(const bf16_t* __restrict__ Abase, int lda, long strA,
             const bf16_t* __restrict__ Bbase, int ldb, long strB,
             void* __restrict__ outp, long strO, int ldo,
             const float* __restrict__ x0, const float* __restrict__ x1,
             const float* __restrict__ x2,
             const int* __restrict__ maskp, float* __restrict__ tmaxp,
             int K) {
  extern __shared__ __align__(16) char smem[];
  const int tid = threadIdx.x;
  const int lane = tid & 63, w = tid >> 6;
  const int wm = w >> 2, wn = w & 3;
  const int fr = lane & 15, fs = lane >> 4;
  const int z = blockIdx.z;
  const int mbase = blockIdx.y * 256, nbase = blockIdx.x * 256;

  const bf16_t* A  = Abase + (size_t)z * strA;
  const bf16_t* Bt = Bbase + (size_t)z * strB;

  // staging per-thread global offsets (source pre-swizzled; LDS dest linear)
  int off_g[2][2][2];  // [matrix][half][j]
  int lds_off[2];
#pragma unroll
  for (int j = 0; j < 2; ++j) {
    int c = j * 512 + tid;
    int row = c >> 3;
    int sg = (c & 7) ^ (row & 7);
    off_g[0][0][j] = (mbase + row) * lda + sg * 8;
    off_g[0][1][j] = (mbase + 128 + row) * lda + sg * 8;
    off_g[1][0][j] = (nbase + row) * ldb + sg * 8;
    off_g[1][1][j] = (nbase + 128 + row) * ldb + sg * 8;
    lds_off[j] = (j * 512 + w * 64) * 16;
  }

#define STAGE(mat, h, srcK, bsel) do {                                        \
    const bf16_t* gsrc = (mat) ? Bt : A;                                      \
    char* lb = smem + (bsel) * 65536 + (mat) * 32768 + (h) * 16384;           \
    gload_lds16(gsrc + off_g[mat][h][0] + (srcK) * 64, (bf16_t*)(lb + lds_off[0])); \
    gload_lds16(gsrc + off_g[mat][h][1] + (srcK) * 64, (bf16_t*)(lb + lds_off[1])); \
  } while (0)

  bf16x8 af[4][2], bfv[2][2][2];
  const int swz0 = (fs ^ (fr & 7)) * 16;
  const int swz1 = ((4 + fs) ^ (fr & 7)) * 16;

#define LOAD_A(bsel, mh) do {                                                 \
    const char* ab = smem + (bsel) * 65536 + wm * 16384;                      \
    _Pragma("unroll")                                                         \
    for (int i = 0; i < 4; ++i) {                                             \
      int rb = ((mh) * 64 + i * 16 + fr) * 128;                               \
      af[i][0] = *(const bf16x8*)(ab + rb + swz0);                            \
      af[i][1] = *(const bf16x8*)(ab + rb + swz1);                            \
    }                                                                         \
  } while (0)

#define LOAD_B(bsel, nh) do {                                                 \
    const char* bb = smem + (bsel) * 65536 + 32768 + (wn >> 1) * 16384;       \
    _Pragma("unroll")                                                         \
    for (int j = 0; j < 2; ++j) {                                             \
      int rb = ((wn & 1) * 64 + (nh) * 32 + j * 16 + fr) * 128;               \
      bfv[nh][j][0] = *(const bf16x8*)(bb + rb + swz0);                       \
      bfv[nh][j][1] = *(const bf16x8*)(bb + rb + swz1);                       \
    }                                                                         \
  } while (0)

#define MFMA_Q(mh, nh) do {                                                   \
    __builtin_amdgcn_s_setprio(1);                                            \
    _Pragma("unroll")                                                         \
    for (int i = 0; i < 4; ++i)                                               \
    _Pragma("unroll")                                                         \
    for (int j = 0; j < 2; ++j) {                                             \
      acc[(mh)*4+i][(nh)*2+j] = __builtin_amdgcn_mfma_f32_16x16x32_bf16(      \
          af[i][0], bfv[nh][j][0], acc[(mh)*4+i][(nh)*2+j], 0, 0, 0);         \
      acc[(mh)*4+i][(nh)*2+j] = __builtin_amdgcn_mfma_f32_16x16x32_bf16(      \
          af[i][1], bfv[nh][j][1], acc[(mh)*4+i][(nh)*2+j], 0, 0, 0);         \
    }                                                                         \
    __builtin_amdgcn_s_setprio(0);                                            \
  } while (0)

  f32x4 acc[8][4] = {};
  const int NK = K >> 6, NKm1 = NK - 1;

  // prologue
  STAGE(0, 0, 0, 0); STAGE(0, 1, 0, 0); STAGE(1, 0, 0, 0); STAGE(1, 1, 0, 0);
  STAGE(1, 0, 1, 1); STAGE(0, 0, 1, 1);
  VMW4(); BARRIER();

  for (int kt = 0; kt < NK; ++kt) {
    const int b = kt & 1;
    const int k1 = (kt + 1 < NK) ? kt + 1 : NKm1;
    const int k2 = (kt + 2 < NK) ? kt + 2 : NKm1;
    // ph0: quadrant (0,0)
    LOAD_A(b, 0); LOAD_B(b, 0);
    STAGE(1, 1, k1, b ^ 1);
    BARRIER();
    MFMA_Q(0, 0);
    BARRIER();
    // ph1: quadrant (0,1)
    LOAD_B(b, 1);
    STAGE(0, 1, k1, b ^ 1);
    BARRIER();
    MFMA_Q(0, 1);
    BARRIER();
    // ph2: quadrant (1,1)
    LOAD_A(b, 1);
    STAGE(1, 0, k2, b);
    BARRIER();
    MFMA_Q(1, 1);
    BARRIER();
    // ph3: quadrant (1,0) — A(mh1) in regs, B(nh0) still live from ph0
    STAGE(0, 0, k2, b);
    BARRIER();
    MFMA_Q(1, 0);
    VMW4();
    BARRIER();
  }

  // ---- epilogues ----  C/D frag: col = fr, row = fs*4 + jj
  const int r0 = mbase + wm * 128;
  const int c0 = nbase + wn * 64;

  if constexpr (MODE == MODE_PROJ) {
    const float* bias = (z == 0) ? x0 : (z == 1) ? x1 : x2;
    const float scale = (z == 0) ? 0.03125f : 1.0f;
    if (z < 2) {
      bf16_t* o = (bf16_t*)outp + (size_t)z * strO;
#pragma unroll
      for (int nf = 0; nf < 4; ++nf) {
        int c = c0 + nf * 16 + fr;
        float bv = bias[c];
#pragma unroll
        for (int mf = 0; mf < 8; ++mf) {
          int rr = r0 + mf * 16 + fs * 4;
#pragma unroll
          for (int jj = 0; jj < 4; ++jj)
            o[(size_t)(rr + jj) * ldo + c] = f2bf((acc[mf][nf][jj] + bv) * scale);
        }
      }
    } else {  // V: write transposed per batch -> Vt[b][c][r&2047]
      bf16_t* o = (bf16_t*)outp + 2 * strO;
#pragma unroll
      for (int nf = 0; nf < 4; ++nf) {
        int c = c0 + nf * 16 + fr;
        float bv = bias[c];
#pragma unroll
        for (int mf = 0; mf < 8; ++mf) {
          int rg = r0 + mf * 16 + fs * 4;
          int bidx = rg >> 11, rl = rg & (L_ - 1);
          union { bf16_t h[4]; ushort4 u; } pk;
#pragma unroll
          for (int jj = 0; jj < 4; ++jj) pk.h[jj] = f2bf(acc[mf][nf][jj] + bv);
          *(ushort4*)&o[(size_t)bidx * D_ * L_ + (size_t)c * L_ + rl] = pk.u;
        }
      }
    }
  } else if constexpr (MODE == MODE_S) {
    bf16_t* o = (bf16_t*)outp + (size_t)z * strO;
    const int* mk = maskp + (size_t)z * L_ * L_;
    float* tm = tmaxp + (size_t)z * L_ * 32;
#pragma unroll
    for (int mf = 0; mf < 8; ++mf) {
#pragma unroll
      for (int jj = 0; jj < 4; ++jj) {
        int r = r0 + mf * 16 + fs * 4 + jj;
        float rowm = -3.0e38f;
#pragma unroll
        for (int nf = 0; nf < 4; ++nf) {
          int c = c0 + nf * 16 + fr;
          float v = acc[mf][nf][jj];
          if (mk[(size_t)r * L_ + c] == 0) v = -1e20f;
          rowm = fmaxf(rowm, v);
          o[(size_t)r * ldo + c] = f2bf(v);
        }
#pragma unroll
        for (int off = 8; off; off >>= 1) rowm = fmaxf(rowm, __shfl_xor(rowm, off, 16));
        if (fr == 0) tm[r * 32 + blockIdx.x * 4 + wn] = rowm;
      }
    }
  } else if constexpr (MODE == MODE_PV) {
    bf16_t* o = (bf16_t*)outp + (size_t)z * strO;
    const float* rs = x0 + (size_t)z * L_;
#pragma unroll
    for (int mf = 0; mf < 8; ++mf) {
#pragma unroll
      for (int jj = 0; jj < 4; ++jj) {
        int r = r0 + mf * 16 + fs * 4 + jj;
        float inv = 1.0f / rs[r];
#pragma unroll
        for (int nf = 0; nf < 4; ++nf) {
          int c = c0 + nf * 16 + fr;
          o[(size_t)r * ldo + c] = f2bf(acc[mf][nf][jj] * inv);
        }
      }
    }
  } else {  // MODE_OUT
    float* o = (float*)outp;
#pragma unroll
    for (int nf = 0; nf < 4; ++nf) {
      int c = c0 + nf * 16 + fr;
      float bv = x0[c];
#pragma unroll
      for (int mf = 0; mf < 8; ++mf) {
        int rr = r0 + mf * 16 + fs * 4;
#pragma unroll
        for (int jj = 0; jj < 4; ++jj)
          o[(size_t)(rr + jj) * ldo + c] = acc[mf][nf][jj] + bv;
      }
    }
  }
#undef STAGE
#undef LOAD_A
#undef LOAD_B
#undef MFMA_Q
}

extern "C" void kernel_launch(void* const* d_in, const int* in_sizes, int n_in,
                              void* d_out, int out_size, void* d_ws, size_t ws_size,
                              hipStream_t stream) {
  const float* query = (const float*)d_in[0];
  const float* keyi  = (const float*)d_in[1];
  const float* value = (const float*)d_in[2];
  const int*   mask  = (const int*)d_in[3];
  const float* Wq = (const float*)d_in[4];
  const float* bq = (const float*)d_in[5];
  const float* Wk = (const float*)d_in[6];
  const float* bk = (const float*)d_in[7];
  const float* Wv = (const float*)d_in[8];
  const float* bv = (const float*)d_in[9];
  const float* Wo = (const float*)d_in[10];
  const float* bo = (const float*)d_in[11];

  bf16_t* ws = (bf16_t*)d_ws;
  const size_t NE = (size_t)M_FLAT * D_;  // 8388608 elts
  const size_t WE = (size_t)D_ * D_;      // 1048576 elts
  bf16_t* XQ  = ws;                 // bf16 query  (dead after projections)
  bf16_t* XK  = ws + NE;
  bf16_t* XV  = ws + 2 * NE;
  bf16_t* WQT = ws + 3 * NE;
  bf16_t* WKT = WQT + WE;
  bf16_t* WVT = WKT + WE;
  bf16_t* WOT = WVT + WE;
  bf16_t* Qb  = WOT + WE;           // (B*L, D) bf16, pre-scaled 1/32
  bf16_t* Kb  = Qb + NE;            // (B*L, D)
  bf16_t* Vt  = Kb + NE;            // per batch (D, L)   (= Qb + 2*NE)
  bf16_t* Sb  = ws;                 // S/P (B, L, L)  — overlaps XQ+XK
  bf16_t* Ob  = ws + 2 * NE;        // attn out (B*L, D) — overlaps XV
  float* tmaxp = (float*)(Vt + NE);               // (B*L, 32)
  float* rowm  = tmaxp + (size_t)B_ * L_ * 32;    // (B*L)
  float* rsump = rowm + (size_t)B_ * L_;          // (B*L)

  // allow 128KB dynamic LDS (idempotent; not a stream op, graph-capture-safe)
  hipFuncSetAttribute((const void*)gemm256<MODE_PROJ>,
                      hipFuncAttributeMaxDynamicSharedMemorySize, 131072);
  hipFuncSetAttribute((const void*)gemm256<MODE_S>,
                      hipFuncAttributeMaxDynamicSharedMemorySize, 131072);
  hipFuncSetAttribute((const void*)gemm256<MODE_PV>,
                      hipFuncAttributeMaxDynamicSharedMemorySize, 131072);
  hipFuncSetAttribute((const void*)gemm256<MODE_OUT>,
                      hipFuncAttributeMaxDynamicSharedMemorySize, 131072);

  // 1) converts
  cvt_bf16<<<dim3(4096), dim3(256), 0, stream>>>(query, XQ);
  cvt_bf16<<<dim3(4096), dim3(256), 0, stream>>>(keyi, XK);
  cvt_bf16<<<dim3(4096), dim3(256), 0, stream>>>(value, XV);
  // 2) weight transposes
  transpose_cvt<<<dim3(32, 32), dim3(32, 8), 0, stream>>>(Wq, WQT);
  transpose_cvt<<<dim3(32, 32), dim3(32, 8), 0, stream>>>(Wk, WKT);
  transpose_cvt<<<dim3(32, 32), dim3(32, 8), 0, stream>>>(Wv, WVT);
  transpose_cvt<<<dim3(32, 32), dim3(32, 8), 0, stream>>>(Wo, WOT);
  // 3) batched QKV projections (z: 0=Q, 1=K, 2=V->Vt)
  gemm256<MODE_PROJ><<<dim3(4, 32, 3), 512, 131072, stream>>>(
      XQ, D_, (long)NE, WQT, D_, (long)WE, Qb, (long)NE, D_,
      bq, bk, bv, nullptr, nullptr, D_);
  // 4) S = Q K^T (+mask, per-tile rowmax)
  gemm256<MODE_S><<<dim3(8, 8, 4), 512, 131072, stream>>>(
      Qb, D_, (long)L_ * D_, Kb, D_, (long)L_ * D_, Sb, (long)L_ * L_, L_,
      nullptr, nullptr, nullptr, mask, tmaxp, D_);
  // 5) row max reduce
  rowmax_k<<<dim3(32), dim3(256), 0, stream>>>(tmaxp, rowm);
  // 6) softmax rows (P in place, row sums)
  softmax_row<<<dim3(B_ * L_), dim3(256), 0, stream>>>(Sb, rowm, rsump);
  // 7) O = P V (divide by row sum in epilogue)
  gemm256<MODE_PV><<<dim3(4, 8, 4), 512, 131072, stream>>>(
      Sb, L_, (long)L_ * L_, Vt, L_, (long)D_ * L_, Ob, (long)L_ * D_, D_,
      rsump, nullptr, nullptr, nullptr, nullptr, L_);
  // 8) final projection -> fp32 d_out
  gemm256<MODE_OUT><<<dim3(4, 32, 1), 512, 131072, stream>>>(
      Ob, D_, 0, WOT, D_, 0, d_out, 0, D_,
      bo, nullptr, nullptr, nullptr, nullptr, D_);
}